// Round 1
// 320.258 us; speedup vs baseline: 1.0313x; 1.0313x over previous
//
#include <hip/hip_runtime.h>
#include <hip/hip_bf16.h>

// Problem: B=16, N=4096, D=768, M=8
//   xn = LayerNorm(x) * gamma + beta          [B,N,D]
//   sim = (queries @ xn^T) * D^-0.5           [B,M,N]
//   attn = softmax(sim, axis=-1)
//   out = attn @ xn                           [B,M,D]
// All I/O fp32. Compute fp32.
//
// Round-1 (this session): k_out restructured with gamma/beta/mu folding:
//   out[b,m,d] = g_d*(sum_n w_mn x_nd - wmu_m) + beta_d,  w = attn*rstd
// so the inner loop is pure x-stream + FMA (no xn recompute), atomics cut
// 4x via d-split blocks. k_ln_sim byte-identical to the 330us baseline for
// attribution.

#define B_ 16
#define N_ 4096
#define D_ 768
#define M_ 8
#define EPS_ 1e-3f
#define SCALE_ 0.03608439182435161f  // 768^-0.5

// ws layout (floats)
#define SIM_OFF   0            // B*M*N = 524288 floats
#define MEAN_OFF  524288       // B*N   =  65536
#define RSTD_OFF  589824       // B*N   =  65536
#define SMAX_OFF  655360       // B*M   =    128
#define SINV_OFF  655488       // B*M   =    128

// ---------------- kernel 1: LayerNorm stats + sim = q . xn ----------------
// one wave per row; lane owns 12 cols (3 float4).
// gamma folded into q: sim_m = SCALE*(rs*(dot(qg,v) - mu*qgs_m) + qb_m)
// -> per-row dot is independent of the stats reduction (overlapped), no
//    per-element xn compute, g/b not live in the loop.
__global__ __launch_bounds__(256) void k_ln_sim(
    const float* __restrict__ x,
    const float* __restrict__ q,
    const float* __restrict__ gm,
    const float* __restrict__ bt,
    float* __restrict__ sim, float* __restrict__ meanb, float* __restrict__ rstdb)
{
    const int lane = threadIdx.x & 63;
    const int gw   = blockIdx.x * 4 + (threadIdx.x >> 6);
    const int total_waves = gridDim.x * 4;

    // init: per-lane qg = q*gamma; wave-wide qgs_m = sum(q*g), qb_m = sum(q*b)
    float qg[8][12];
    float qgs[8], qb[8];
#pragma unroll
    for (int m = 0; m < 8; m++) { qgs[m] = 0.f; qb[m] = 0.f; }
#pragma unroll
    for (int i = 0; i < 3; i++) {
        const int c4 = (lane + i * 64) * 4;
        float4 gv = *(const float4*)(gm + c4);
        float4 bv = *(const float4*)(bt + c4);
#pragma unroll
        for (int m = 0; m < 8; m++) {
            float4 qv = *(const float4*)(q + m * D_ + c4);
            qg[m][i * 4 + 0] = qv.x * gv.x;
            qg[m][i * 4 + 1] = qv.y * gv.y;
            qg[m][i * 4 + 2] = qv.z * gv.z;
            qg[m][i * 4 + 3] = qv.w * gv.w;
            qgs[m] += qg[m][i * 4 + 0] + qg[m][i * 4 + 1] + qg[m][i * 4 + 2] + qg[m][i * 4 + 3];
            qb[m]  += qv.x * bv.x + qv.y * bv.y + qv.z * bv.z + qv.w * bv.w;
        }
    }
#pragma unroll
    for (int mask = 32; mask; mask >>= 1)
#pragma unroll
        for (int m = 0; m < 8; m++) {
            qgs[m] += __shfl_xor(qgs[m], mask, 64);
            qb[m]  += __shfl_xor(qb[m],  mask, 64);
        }
    // pre-select this lane's octet values (m = lane>>3) via static tree
    const int mo = lane >> 3;
    const float qgs_sel =
        (mo & 4) ? ((mo & 2) ? ((mo & 1) ? qgs[7] : qgs[6]) : ((mo & 1) ? qgs[5] : qgs[4]))
                 : ((mo & 2) ? ((mo & 1) ? qgs[3] : qgs[2]) : ((mo & 1) ? qgs[1] : qgs[0]));
    const float qbs = SCALE_ *
        ((mo & 4) ? ((mo & 2) ? ((mo & 1) ? qb[7] : qb[6]) : ((mo & 1) ? qb[5] : qb[4]))
                  : ((mo & 2) ? ((mo & 1) ? qb[3] : qb[2]) : ((mo & 1) ? qb[1] : qb[0])));

    const bool hi32 = (lane & 32) != 0;
    const bool hi16 = (lane & 16) != 0;
    const bool hi8  = (lane & 8)  != 0;

    for (int row = gw; row < B_ * N_; row += total_waves) {
        const float* xr = x + (size_t)row * D_;
        float v[12];
#pragma unroll
        for (int i = 0; i < 3; i++) {
            float4 p = *(const float4*)(xr + (lane + i * 64) * 4);
            v[i * 4 + 0] = p.x; v[i * 4 + 1] = p.y;
            v[i * 4 + 2] = p.z; v[i * 4 + 3] = p.w;
        }
        // stats partials and dot partials — independent chains
        float s = 0.f, s2 = 0.f;
#pragma unroll
        for (int k = 0; k < 12; k++) { s += v[k]; s2 += v[k] * v[k]; }
        float acc[8];
#pragma unroll
        for (int m = 0; m < 8; m++) acc[m] = 0.f;
#pragma unroll
        for (int k = 0; k < 12; k++)
#pragma unroll
            for (int m = 0; m < 8; m++) acc[m] = fmaf(qg[m][k], v[k], acc[m]);

        // stats: full butterfly (all lanes need mean/rstd)
#pragma unroll
        for (int mask = 32; mask; mask >>= 1) {
            s  += __shfl_xor(s,  mask, 64);
            s2 += __shfl_xor(s2, mask, 64);
        }
        const float mean = s * (1.0f / 768.0f);
        float var = s2 * (1.0f / 768.0f) - mean * mean;
        var = fmaxf(var, 0.0f);
        const float rstd = rsqrtf(var + EPS_);

        // dot: thinning reduction, 8 values -> lane octet (lane>>3)==m
        float a0 = hi32 ? acc[4] : acc[0], sA0 = hi32 ? acc[0] : acc[4];
        float a1 = hi32 ? acc[5] : acc[1], sA1 = hi32 ? acc[1] : acc[5];
        float a2 = hi32 ? acc[6] : acc[2], sA2 = hi32 ? acc[2] : acc[6];
        float a3 = hi32 ? acc[7] : acc[3], sA3 = hi32 ? acc[3] : acc[7];
        a0 += __shfl_xor(sA0, 32, 64);
        a1 += __shfl_xor(sA1, 32, 64);
        a2 += __shfl_xor(sA2, 32, 64);
        a3 += __shfl_xor(sA3, 32, 64);
        float b0 = hi16 ? a2 : a0, sB0 = hi16 ? a0 : a2;
        float b1 = hi16 ? a3 : a1, sB1 = hi16 ? a1 : a3;
        b0 += __shfl_xor(sB0, 16, 64);
        b1 += __shfl_xor(sB1, 16, 64);
        float c0 = hi8 ? b1 : b0, sC0 = hi8 ? b0 : b1;
        c0 += __shfl_xor(sC0, 8, 64);
        c0 += __shfl_xor(c0, 4, 64);
        c0 += __shfl_xor(c0, 2, 64);
        c0 += __shfl_xor(c0, 1, 64);

        const int b = row >> 12, n = row & (N_ - 1);
        if (lane == 0) {
            meanb[row] = mean;
            rstdb[row] = rstd;
        }
        if ((lane & 7) == 0) {
            // sim = SCALE*(rs*(c0 - mu*qgs) + qb)
            sim[(size_t)((b * 8 + mo) << 12) + n] =
                fmaf(rstd * SCALE_, c0 - mean * qgs_sel, qbs);
        }
    }
}

// ---------------- kernel 2: per-(b,m) softmax stats + out row init ----------------
// computes mx, 1/sum, and wmu = sum_n attn_mn * rstd_n * mu_n.
// initializes out[b,m,d] = beta[d] - gamma[d]*wmu  (exact: softmax rows sum to 1)
__global__ __launch_bounds__(256) void k_stats(
    const float* __restrict__ sim,
    const float* __restrict__ meanb,
    const float* __restrict__ rstdb,
    const float* __restrict__ gm,
    const float* __restrict__ bt,
    float* __restrict__ smax, float* __restrict__ sinv,
    float* __restrict__ out)
{
    const int bm = blockIdx.x;            // b*8 + m, 0..127
    const int b  = bm >> 3;
    const float* p  = sim   + ((size_t)bm << 12);
    const float* mu = meanb + ((size_t)b  << 12);
    const float* rs = rstdb + ((size_t)b  << 12);
    const int t = threadIdx.x;
    const int lane = t & 63, wave = t >> 6;
    __shared__ float red[8];

    float v[16];
    float mx = -3.4e38f;
#pragma unroll
    for (int i = 0; i < 16; i++) { v[i] = p[t + i * 256]; mx = fmaxf(mx, v[i]); }
#pragma unroll
    for (int mask = 32; mask; mask >>= 1) mx = fmaxf(mx, __shfl_xor(mx, mask, 64));
    if (lane == 0) red[wave] = mx;
    __syncthreads();
    mx = fmaxf(fmaxf(red[0], red[1]), fmaxf(red[2], red[3]));
    __syncthreads();

    float s = 0.f, smu = 0.f;
#pragma unroll
    for (int i = 0; i < 16; i++) {
        const int n = t + i * 256;
        const float e = __expf(v[i] - mx);
        s += e;
        smu = fmaf(e, rs[n] * mu[n], smu);
    }
#pragma unroll
    for (int mask = 32; mask; mask >>= 1) {
        s   += __shfl_xor(s,   mask, 64);
        smu += __shfl_xor(smu, mask, 64);
    }
    if (lane == 0) { red[wave] = s; red[wave + 4] = smu; }
    __syncthreads();
    s   = red[0] + red[1] + red[2] + red[3];
    smu = red[4] + red[5] + red[6] + red[7];
    const float inv = 1.0f / s;
    const float wmu = smu * inv;
    if (t == 0) { smax[bm] = mx; sinv[bm] = inv; }

    // init this (b,m) output row: beta - gamma*wmu
    float* o = out + (size_t)bm * D_;
#pragma unroll
    for (int k = 0; k < 3; k++) {
        const int d = t + k * 256;
        o[d] = fmaf(-gm[d], wmu, bt[d]);
    }
}

// ---------------- kernel 3: out += g_d * sum_n w_mn * x_nd ----------------
// grid (16 b, 3 dchunk, 16 nchunk) = 768 blocks (3/CU). Thread owns ONE
// column d = dc*256+t; w[8][256] staged in LDS (broadcast float4 reads).
// Inner loop: 1 global load + 8 FMA per row. Atomics: 8 per thread
// (1.57M total, 16-way per address, m-rotated by nchunk).
__global__ __launch_bounds__(256) void k_out(
    const float* __restrict__ x,
    const float* __restrict__ gm,
    const float* __restrict__ sim,
    const float* __restrict__ rstdb,
    const float* __restrict__ smax,
    const float* __restrict__ sinv,
    float* __restrict__ out)
{
    __shared__ __align__(16) float w_s[8 * 256];   // [m][nn], 8 KB

    const int b  = blockIdx.x;
    const int dc = blockIdx.y;
    const int nc = blockIdx.z;
    const int t  = threadIdx.x;
    const int n0 = nc << 8;
    const int d  = (dc << 8) + t;

    // stage w[m][nn] = exp(sim - mx) * sinv * rstd
    const float rs_t = rstdb[((size_t)b << 12) + n0 + t];
#pragma unroll
    for (int m = 0; m < 8; m++) {
        const int bm = (b << 3) + m;
        const float v = sim[((size_t)bm << 12) + n0 + t];
        w_s[(m << 8) + t] = __expf(v - smax[bm]) * sinv[bm] * rs_t;
    }
    __syncthreads();

    float acc[8];
#pragma unroll
    for (int m = 0; m < 8; m++) acc[m] = 0.f;

    const float* xp = x + ((size_t)(b * N_ + n0)) * D_ + d;
#pragma unroll 2
    for (int nn = 0; nn < 256; nn += 4) {
        const float x0 = xp[(size_t)(nn + 0) * D_];
        const float x1 = xp[(size_t)(nn + 1) * D_];
        const float x2 = xp[(size_t)(nn + 2) * D_];
        const float x3 = xp[(size_t)(nn + 3) * D_];
#pragma unroll
        for (int m = 0; m < 8; m++) {
            const float4 wv = *(const float4*)&w_s[(m << 8) + nn];
            acc[m] = fmaf(wv.x, x0, acc[m]);
            acc[m] = fmaf(wv.y, x1, acc[m]);
            acc[m] = fmaf(wv.z, x2, acc[m]);
            acc[m] = fmaf(wv.w, x3, acc[m]);
        }
    }

    const float g = gm[d];
#pragma unroll
    for (int mm = 0; mm < 8; mm++) {
        const int m = (mm + nc) & 7;    // rotate to spread atomic contention
        atomicAdd(out + (size_t)((b << 3) + m) * D_ + d, g * acc[m]);
    }
}

extern "C" void kernel_launch(void* const* d_in, const int* in_sizes, int n_in,
                              void* d_out, int out_size, void* d_ws, size_t ws_size,
                              hipStream_t stream)
{
    const float* x  = (const float*)d_in[0];
    const float* q  = (const float*)d_in[1];
    const float* gm = (const float*)d_in[2];
    const float* bt = (const float*)d_in[3];
    float* out = (float*)d_out;

    float* ws    = (float*)d_ws;
    float* sim   = ws + SIM_OFF;
    float* meanb = ws + MEAN_OFF;
    float* rstdb = ws + RSTD_OFF;
    float* smax  = ws + SMAX_OFF;
    float* sinv  = ws + SINV_OFF;

    k_ln_sim<<<2048, 256, 0, stream>>>(x, q, gm, bt, sim, meanb, rstdb);
    k_stats<<<B_ * M_, 256, 0, stream>>>(sim, meanb, rstdb, gm, bt, smax, sinv, out);
    k_out<<<dim3(16, 3, 16), 256, 0, stream>>>(x, gm, sim, rstdb, smax, sinv, out);
}

// Round 2
// 316.677 us; speedup vs baseline: 1.0429x; 1.0113x over previous
//
#include <hip/hip_runtime.h>
#include <hip/hip_bf16.h>

// Problem: B=16, N=4096, D=768, M=8
//   xn = LayerNorm(x) * gamma + beta          [B,N,D]
//   sim = (queries @ xn^T) * D^-0.5           [B,M,N]
//   attn = softmax(sim, axis=-1)
//   out = attn @ xn                           [B,M,D]
// All I/O fp32. Compute fp32.
//
// Round-2: k_ln_sim register diet. The q*gamma table (96 VGPRs/thread in
// round 1 -> ~140 total -> 2 waves/SIMD) is block-shared data; moved to
// 24 KB LDS staged once per block. VGPR ~55 -> 6 blocks/CU (24 waves/CU,
// 3x occupancy). Grid 1536 = exactly 6/CU, single residency pass.
// k_stats / k_out byte-identical to round 1 for attribution.

#define B_ 16
#define N_ 4096
#define D_ 768
#define M_ 8
#define EPS_ 1e-3f
#define SCALE_ 0.03608439182435161f  // 768^-0.5

// ws layout (floats)
#define SIM_OFF   0            // B*M*N = 524288 floats
#define MEAN_OFF  524288       // B*N   =  65536
#define RSTD_OFF  589824       // B*N   =  65536
#define SMAX_OFF  655360       // B*M   =    128
#define SINV_OFF  655488       // B*M   =    128

// ---------------- kernel 1: LayerNorm stats + sim = q . xn ----------------
// one wave per row; lane owns 12 cols (3 float4).
// gamma folded into q: sim_m = SCALE*(rs*(dot(qg,v) - mu*qgs_m) + qb_m)
// qg table lives in LDS (block-shared), freeing ~96 VGPRs -> 3x occupancy.
__global__ __launch_bounds__(256) void k_ln_sim(
    const float* __restrict__ x,
    const float* __restrict__ q,
    const float* __restrict__ gm,
    const float* __restrict__ bt,
    float* __restrict__ sim, float* __restrict__ meanb, float* __restrict__ rstdb)
{
    __shared__ __align__(16) float qg_s[8][768];   // 24 KB
    __shared__ float qgs_s[8], qb_s[8];

    const int lane = threadIdx.x & 63;
    const int wv   = threadIdx.x >> 6;             // 0..3
    const int gw   = blockIdx.x * 4 + wv;
    const int total_waves = gridDim.x * 4;

    // ---- init: wave wv prepares m0=2wv, m1=2wv+1 (each wave's lanes cover all 768 cols)
    {
        const int m0 = wv * 2, m1 = m0 + 1;
        float qgs0 = 0.f, qb0 = 0.f, qgs1 = 0.f, qb1 = 0.f;
#pragma unroll
        for (int i = 0; i < 3; i++) {
            const int c4 = (lane + i * 64) * 4;
            const float4 gv = *(const float4*)(gm + c4);
            const float4 bv = *(const float4*)(bt + c4);
            const float4 q0 = *(const float4*)(q + m0 * D_ + c4);
            const float4 q1 = *(const float4*)(q + m1 * D_ + c4);
            float4 g0, g1;
            g0.x = q0.x * gv.x; g0.y = q0.y * gv.y; g0.z = q0.z * gv.z; g0.w = q0.w * gv.w;
            g1.x = q1.x * gv.x; g1.y = q1.y * gv.y; g1.z = q1.z * gv.z; g1.w = q1.w * gv.w;
            *(float4*)&qg_s[m0][c4] = g0;
            *(float4*)&qg_s[m1][c4] = g1;
            qgs0 += g0.x + g0.y + g0.z + g0.w;
            qgs1 += g1.x + g1.y + g1.z + g1.w;
            qb0  += q0.x * bv.x + q0.y * bv.y + q0.z * bv.z + q0.w * bv.w;
            qb1  += q1.x * bv.x + q1.y * bv.y + q1.z * bv.z + q1.w * bv.w;
        }
#pragma unroll
        for (int mask = 32; mask; mask >>= 1) {
            qgs0 += __shfl_xor(qgs0, mask, 64);
            qgs1 += __shfl_xor(qgs1, mask, 64);
            qb0  += __shfl_xor(qb0,  mask, 64);
            qb1  += __shfl_xor(qb1,  mask, 64);
        }
        if (lane == 0) {
            qgs_s[m0] = qgs0; qgs_s[m1] = qgs1;
            qb_s[m0]  = qb0;  qb_s[m1]  = qb1;
        }
    }
    __syncthreads();

    const int mo = lane >> 3;
    const float qgs_sel = qgs_s[mo];
    const float qbs     = SCALE_ * qb_s[mo];

    const bool hi32 = (lane & 32) != 0;
    const bool hi16 = (lane & 16) != 0;
    const bool hi8  = (lane & 8)  != 0;

    for (int row = gw; row < B_ * N_; row += total_waves) {
        const float* xr = x + (size_t)row * D_;
        float v[12];
#pragma unroll
        for (int i = 0; i < 3; i++) {
            float4 p = *(const float4*)(xr + (lane + i * 64) * 4);
            v[i * 4 + 0] = p.x; v[i * 4 + 1] = p.y;
            v[i * 4 + 2] = p.z; v[i * 4 + 3] = p.w;
        }
        // stats partials — independent of the dot chain
        float s = 0.f, s2 = 0.f;
#pragma unroll
        for (int k = 0; k < 12; k++) { s += v[k]; s2 += v[k] * v[k]; }

        float acc[8];
#pragma unroll
        for (int m = 0; m < 8; m++) acc[m] = 0.f;
#pragma unroll
        for (int i = 0; i < 3; i++) {
            const int c4 = (lane + i * 64) * 4;
#pragma unroll
            for (int m = 0; m < 8; m++) {
                const float4 qv = *(const float4*)&qg_s[m][c4];   // ds_read_b128
                acc[m] = fmaf(qv.x, v[i * 4 + 0], acc[m]);
                acc[m] = fmaf(qv.y, v[i * 4 + 1], acc[m]);
                acc[m] = fmaf(qv.z, v[i * 4 + 2], acc[m]);
                acc[m] = fmaf(qv.w, v[i * 4 + 3], acc[m]);
            }
        }

        // stats: full butterfly (all lanes need mean/rstd)
#pragma unroll
        for (int mask = 32; mask; mask >>= 1) {
            s  += __shfl_xor(s,  mask, 64);
            s2 += __shfl_xor(s2, mask, 64);
        }
        const float mean = s * (1.0f / 768.0f);
        float var = s2 * (1.0f / 768.0f) - mean * mean;
        var = fmaxf(var, 0.0f);
        const float rstd = rsqrtf(var + EPS_);

        // dot: thinning reduction, 8 values -> lane octet (lane>>3)==m
        float a0 = hi32 ? acc[4] : acc[0], sA0 = hi32 ? acc[0] : acc[4];
        float a1 = hi32 ? acc[5] : acc[1], sA1 = hi32 ? acc[1] : acc[5];
        float a2 = hi32 ? acc[6] : acc[2], sA2 = hi32 ? acc[2] : acc[6];
        float a3 = hi32 ? acc[7] : acc[3], sA3 = hi32 ? acc[3] : acc[7];
        a0 += __shfl_xor(sA0, 32, 64);
        a1 += __shfl_xor(sA1, 32, 64);
        a2 += __shfl_xor(sA2, 32, 64);
        a3 += __shfl_xor(sA3, 32, 64);
        float b0 = hi16 ? a2 : a0, sB0 = hi16 ? a0 : a2;
        float b1 = hi16 ? a3 : a1, sB1 = hi16 ? a1 : a3;
        b0 += __shfl_xor(sB0, 16, 64);
        b1 += __shfl_xor(sB1, 16, 64);
        float c0 = hi8 ? b1 : b0, sC0 = hi8 ? b0 : b1;
        c0 += __shfl_xor(sC0, 8, 64);
        c0 += __shfl_xor(c0, 4, 64);
        c0 += __shfl_xor(c0, 2, 64);
        c0 += __shfl_xor(c0, 1, 64);

        const int b = row >> 12, n = row & (N_ - 1);
        if (lane == 0) {
            meanb[row] = mean;
            rstdb[row] = rstd;
        }
        if ((lane & 7) == 0) {
            // sim = SCALE*(rs*(c0 - mu*qgs) + qb)
            sim[(size_t)((b * 8 + mo) << 12) + n] =
                fmaf(rstd * SCALE_, c0 - mean * qgs_sel, qbs);
        }
    }
}

// ---------------- kernel 2: per-(b,m) softmax stats + out row init ----------------
// computes mx, 1/sum, and wmu = sum_n attn_mn * rstd_n * mu_n.
// initializes out[b,m,d] = beta[d] - gamma[d]*wmu  (exact: softmax rows sum to 1)
__global__ __launch_bounds__(256) void k_stats(
    const float* __restrict__ sim,
    const float* __restrict__ meanb,
    const float* __restrict__ rstdb,
    const float* __restrict__ gm,
    const float* __restrict__ bt,
    float* __restrict__ smax, float* __restrict__ sinv,
    float* __restrict__ out)
{
    const int bm = blockIdx.x;            // b*8 + m, 0..127
    const int b  = bm >> 3;
    const float* p  = sim   + ((size_t)bm << 12);
    const float* mu = meanb + ((size_t)b  << 12);
    const float* rs = rstdb + ((size_t)b  << 12);
    const int t = threadIdx.x;
    const int lane = t & 63, wave = t >> 6;
    __shared__ float red[8];

    float v[16];
    float mx = -3.4e38f;
#pragma unroll
    for (int i = 0; i < 16; i++) { v[i] = p[t + i * 256]; mx = fmaxf(mx, v[i]); }
#pragma unroll
    for (int mask = 32; mask; mask >>= 1) mx = fmaxf(mx, __shfl_xor(mx, mask, 64));
    if (lane == 0) red[wave] = mx;
    __syncthreads();
    mx = fmaxf(fmaxf(red[0], red[1]), fmaxf(red[2], red[3]));
    __syncthreads();

    float s = 0.f, smu = 0.f;
#pragma unroll
    for (int i = 0; i < 16; i++) {
        const int n = t + i * 256;
        const float e = __expf(v[i] - mx);
        s += e;
        smu = fmaf(e, rs[n] * mu[n], smu);
    }
#pragma unroll
    for (int mask = 32; mask; mask >>= 1) {
        s   += __shfl_xor(s,   mask, 64);
        smu += __shfl_xor(smu, mask, 64);
    }
    if (lane == 0) { red[wave] = s; red[wave + 4] = smu; }
    __syncthreads();
    s   = red[0] + red[1] + red[2] + red[3];
    smu = red[4] + red[5] + red[6] + red[7];
    const float inv = 1.0f / s;
    const float wmu = smu * inv;
    if (t == 0) { smax[bm] = mx; sinv[bm] = inv; }

    // init this (b,m) output row: beta - gamma*wmu
    float* o = out + (size_t)bm * D_;
#pragma unroll
    for (int k = 0; k < 3; k++) {
        const int d = t + k * 256;
        o[d] = fmaf(-gm[d], wmu, bt[d]);
    }
}

// ---------------- kernel 3: out += g_d * sum_n w_mn * x_nd ----------------
// grid (16 b, 3 dchunk, 16 nchunk) = 768 blocks (3/CU). Thread owns ONE
// column d = dc*256+t; w[8][256] staged in LDS (broadcast float4 reads).
// Inner loop: 1 global load + 8 FMA per row. Atomics: 8 per thread
// (1.57M total, 16-way per address, m-rotated by nchunk).
__global__ __launch_bounds__(256) void k_out(
    const float* __restrict__ x,
    const float* __restrict__ gm,
    const float* __restrict__ sim,
    const float* __restrict__ rstdb,
    const float* __restrict__ smax,
    const float* __restrict__ sinv,
    float* __restrict__ out)
{
    __shared__ __align__(16) float w_s[8 * 256];   // [m][nn], 8 KB

    const int b  = blockIdx.x;
    const int dc = blockIdx.y;
    const int nc = blockIdx.z;
    const int t  = threadIdx.x;
    const int n0 = nc << 8;
    const int d  = (dc << 8) + t;

    // stage w[m][nn] = exp(sim - mx) * sinv * rstd
    const float rs_t = rstdb[((size_t)b << 12) + n0 + t];
#pragma unroll
    for (int m = 0; m < 8; m++) {
        const int bm = (b << 3) + m;
        const float v = sim[((size_t)bm << 12) + n0 + t];
        w_s[(m << 8) + t] = __expf(v - smax[bm]) * sinv[bm] * rs_t;
    }
    __syncthreads();

    float acc[8];
#pragma unroll
    for (int m = 0; m < 8; m++) acc[m] = 0.f;

    const float* xp = x + ((size_t)(b * N_ + n0)) * D_ + d;
#pragma unroll 2
    for (int nn = 0; nn < 256; nn += 4) {
        const float x0 = xp[(size_t)(nn + 0) * D_];
        const float x1 = xp[(size_t)(nn + 1) * D_];
        const float x2 = xp[(size_t)(nn + 2) * D_];
        const float x3 = xp[(size_t)(nn + 3) * D_];
#pragma unroll
        for (int m = 0; m < 8; m++) {
            const float4 wv = *(const float4*)&w_s[(m << 8) + nn];
            acc[m] = fmaf(wv.x, x0, acc[m]);
            acc[m] = fmaf(wv.y, x1, acc[m]);
            acc[m] = fmaf(wv.z, x2, acc[m]);
            acc[m] = fmaf(wv.w, x3, acc[m]);
        }
    }

    const float g = gm[d];
#pragma unroll
    for (int mm = 0; mm < 8; mm++) {
        const int m = (mm + nc) & 7;    // rotate to spread atomic contention
        atomicAdd(out + (size_t)((b << 3) + m) * D_ + d, g * acc[m]);
    }
}

extern "C" void kernel_launch(void* const* d_in, const int* in_sizes, int n_in,
                              void* d_out, int out_size, void* d_ws, size_t ws_size,
                              hipStream_t stream)
{
    const float* x  = (const float*)d_in[0];
    const float* q  = (const float*)d_in[1];
    const float* gm = (const float*)d_in[2];
    const float* bt = (const float*)d_in[3];
    float* out = (float*)d_out;

    float* ws    = (float*)d_ws;
    float* sim   = ws + SIM_OFF;
    float* meanb = ws + MEAN_OFF;
    float* rstdb = ws + RSTD_OFF;
    float* smax  = ws + SMAX_OFF;
    float* sinv  = ws + SINV_OFF;

    k_ln_sim<<<1536, 256, 0, stream>>>(x, q, gm, bt, sim, meanb, rstdb);
    k_stats<<<B_ * M_, 256, 0, stream>>>(sim, meanb, rstdb, gm, bt, smax, sinv, out);
    k_out<<<dim3(16, 3, 16), 256, 0, stream>>>(x, gm, sim, rstdb, smax, sinv, out);
}